// Round 11
// baseline (695.241 us; speedup 1.0000x reference)
//
#include <hip/hip_runtime.h>
#include <stdint.h>

#define NN 10000      // nodes
#define NE 160000     // edges (paired: e and e^1 are fwd/rev)
#define HID 300
#define NF 133
#define EF 14
#define NG 64

#define BR 64         // edge rows per GEMM block
#define NT 19         // n-tiles of 16 (304 padded cols)
#define WGRAN (NT*64) // 1216 16B-granules of W per k-step
#define CSTRIDE 308   // LDS C-tile column stride (ushorts)
#define THR 512       // 8 waves per block

typedef __bf16 bf16x8 __attribute__((ext_vector_type(8)));
typedef float f32x4 __attribute__((ext_vector_type(4)));

union GR { bf16x8 v; unsigned short s[8]; uint4 u; };

__device__ __forceinline__ float bf2f(unsigned short u) {
  union { unsigned int i; float f; } x; x.i = ((unsigned int)u) << 16; return x.f;
}
__device__ __forceinline__ unsigned short f2bf(float f) {
  union { float f; unsigned int i; } x; x.f = f;
  unsigned int r = x.i + 0x7fffu + ((x.i >> 16) & 1u);
  return (unsigned short)(r >> 16);
}

// ---------------- small utilities ----------------
__global__ void zero_kernel(int* __restrict__ p, int n) {
  int i = blockIdx.x * 256 + threadIdx.x;
  if (i < n) p[i] = 0;
}

// ---------------- CSR build over col ----------------
__global__ void hist_kernel(const int* __restrict__ col, int* __restrict__ cnt) {
  int e = blockIdx.x * 256 + threadIdx.x;
  if (e < NE) atomicAdd(&cnt[col[e]], 1);
}

__global__ void scan_kernel(const int* __restrict__ cnt, int* __restrict__ indptr) {
  __shared__ int part[1024];
  int t = threadIdx.x;
  int base = t * 10;
  int loc[10];
  int s = 0;
  #pragma unroll
  for (int i = 0; i < 10; ++i) {
    int n = base + i;
    int v = (n < NN) ? cnt[n] : 0;
    loc[i] = s; s += v;
  }
  part[t] = s;
  __syncthreads();
  for (int off = 1; off < 1024; off <<= 1) {
    int v = part[t];
    int u = (t >= off) ? part[t - off] : 0;
    __syncthreads();
    part[t] = v + u;
    __syncthreads();
  }
  int pre = (t == 0) ? 0 : part[t - 1];
  #pragma unroll
  for (int i = 0; i < 10; ++i) {
    int n = base + i;
    if (n <= NN) indptr[n] = pre + loc[i];
  }
}

// consumes cnt back to zero (self-restoring across graph replays)
__global__ void scatter_kernel(const int* __restrict__ col, const int* __restrict__ indptr,
                               int* __restrict__ cnt, int* __restrict__ eids) {
  int e = blockIdx.x * 256 + threadIdx.x;
  if (e < NE) {
    int v = col[e];
    int p = atomicSub(&cnt[v], 1) - 1;
    eids[indptr[v] + p] = e;
  }
}

// ---- segment_sum(h[bf16], col) -> a[f32]: vectorized, 3 row-slots/block ----
__global__ __launch_bounds__(256)
void segsum_kernel(const unsigned short* __restrict__ h,
                   const int* __restrict__ indptr, const int* __restrict__ eids,
                   float* __restrict__ a) {
  __shared__ float4 part[3][76];
  const int v = blockIdx.x;
  const int t = threadIdx.x;
  const int beg = indptr[v], end = indptr[v + 1];
  if (t < 225) {
    const int g = t % 75;          // ushort4 granule (cols 4g..4g+3)
    const int s = t / 75;          // row slot 0..2
    const int c4 = g << 2;
    float a0 = 0.f, a1 = 0.f, a2 = 0.f, a3 = 0.f;
    float b0 = 0.f, b1 = 0.f, b2 = 0.f, b3 = 0.f;
    int p = beg + s;
    for (; p + 6 <= end; p += 6) {       // 2 rows per iteration (stride 3)
      const int e0 = eids[p], e1 = eids[p + 3];
      const ushort4 h0v = *(const ushort4*)(h + (size_t)e0 * HID + c4);
      const ushort4 h1v = *(const ushort4*)(h + (size_t)e1 * HID + c4);
      a0 += bf2f(h0v.x); a1 += bf2f(h0v.y); a2 += bf2f(h0v.z); a3 += bf2f(h0v.w);
      b0 += bf2f(h1v.x); b1 += bf2f(h1v.y); b2 += bf2f(h1v.z); b3 += bf2f(h1v.w);
    }
    if (p < end) {                       // tail step 1
      const int e0 = eids[p];
      const ushort4 h0v = *(const ushort4*)(h + (size_t)e0 * HID + c4);
      a0 += bf2f(h0v.x); a1 += bf2f(h0v.y); a2 += bf2f(h0v.z); a3 += bf2f(h0v.w);
      p += 3;
    }
    if (p < end) {                       // tail step 2
      const int e1 = eids[p];
      const ushort4 h1v = *(const ushort4*)(h + (size_t)e1 * HID + c4);
      b0 += bf2f(h1v.x); b1 += bf2f(h1v.y); b2 += bf2f(h1v.z); b3 += bf2f(h1v.w);
    }
    part[s][g] = make_float4(a0 + b0, a1 + b1, a2 + b2, a3 + b3);
  }
  __syncthreads();
  if (t < 75) {
    const float4 p0 = part[0][t], p1 = part[1][t], p2 = part[2][t];
    *(float4*)(a + (size_t)v * HID + (t << 2)) =
        make_float4(p0.x + p1.x + p2.x, p0.y + p1.y + p2.y,
                    p0.z + p1.z + p2.z, p0.w + p1.w + p2.w);
  }
}

// ---------------- weight pre-transpose into MFMA fragment order -------------
// dst granule (kt,nt,lane l) holds W[kt*32 + (l>>4)*8 + i][nt*16 + (l&15)], i=0..7
__global__ void wtrans_kernel(const float* __restrict__ W, int K,
                              unsigned short* __restrict__ dst) {
  const int b = blockIdx.x;          // kt*NT + nt
  const int l = threadIdx.x;         // 0..63
  const int kt = b / NT, nt = b - kt * NT;
  const int k0 = kt * 32 + ((l >> 4) << 3);
  const int n  = (nt << 4) + (l & 15);
  GR g;
  #pragma unroll
  for (int i = 0; i < 8; ++i) {
    const int k = k0 + i;
    float f = (k < K && n < HID) ? W[(size_t)k * HID + n] : 0.f;
    g.s[i] = f2bf(f);
  }
  *(uint4*)(dst + ((size_t)(b * 64 + l) << 3)) = g.u;
}

// ---------------- MFMA GEMM: 8 waves, small acc, 4 waves/SIMD ---------------
// Per block: 64 rows x 304 cols, 8 waves. wave = (etg<<2)|ntg:
//   ntg in [0,4): 5 n-tiles (wave ntg==3 has 4); etg in [0,2): 2 row-tiles.
// acc[5][2] = 40 AGPR -> total regs <=128 -> 4 waves/SIMD (16 waves/CU).
// A staged ONCE into LDS in fragment order [kg][row]x16B (shared by all
// waves); W fragments read direct from L2/L1 (dup across etg pair hits L1).
// MODE 0: edge_init  h0 = relu([x[row]|ea] @ W + b); also copy into h
// MODE 1: conv       h[e] = relu((a[row[e]] - bf(h[e^1])) @ W + b + bf(h0[e]))
//                    in-place on h: reads in staging, writes in epilogue
// MODE 2: node MLP   hn = relu([x|s] @ W + b)  (f32 out)
template<int MODE, int KTILES>
__global__ __launch_bounds__(THR, 4)
void gemm_kernel(const float* __restrict__ xin,
                 const int* __restrict__ rowidx,
                 const float* __restrict__ aux,        // MODE0: edge_attr ; MODE2: s
                 const float* __restrict__ agg,        // MODE1: a
                 const unsigned short* hcur,           // MODE1 in (aliases outA)
                 const unsigned short* __restrict__ h0,
                 const unsigned short* __restrict__ wbt,  // fragment-ordered bf16 W^T
                 const float* __restrict__ bias,
                 unsigned short* outA,
                 unsigned short* outB,
                 float* __restrict__ outF)
{
  constexpr int KEFF = (MODE == 0) ? (NF + EF) : ((MODE == 1) ? HID : (NF + HID));
  constexpr int NKG_A = (KEFF + 7) / 8;           // staged 16B k-granules per row
  constexpr int STAGE_USH = NKG_A * 64 * 8;       // staged-A ushorts
  constexpr int PIECES = STAGE_USH / 4;           // ushort4 pieces
  constexpr int SITER = (PIECES + THR - 1) / THR;
  constexpr int LDS_USH = (STAGE_USH > BR * CSTRIDE) ? STAGE_USH : BR * CSTRIDE;
  __shared__ unsigned short S_lds[LDS_USH];       // A-stage, then C-tile
  __shared__ int rowv[BR];

  const int t = threadIdx.x;
  const int l = t & 63;
  const int wave = t >> 6;           // 0..7
  const int ntg = wave & 3;
  const int etg = wave >> 2;         // 0..1: rows [etg*32, etg*32+32)
  const int lr = l & 15;             // row within 16-tile
  const int lg = l >> 4;             // k-granule within k-step / output col-group
  const int r0 = blockIdx.x * BR;
  const int nt0 = ntg * 5;
  const int ntc = (ntg == 3) ? 4 : 5;

  if (MODE != 2 && t < BR) rowv[t] = rowidx[r0 + t];
  __syncthreads();

  // ---- stage A once; per-thread constants: one source row, one k-phase ----
  // piece s = t + THR*it -> kg=(t>>7)+4*it, row=(t>>1)&63, half=(t&1)
  {
    const int a_row = (t >> 1) & 63;
    const int a_c   = t >> 7;        // 0..3
    const int a_h4  = (t & 1) << 2;
    const int rv    = (MODE == 2) ? (r0 + a_row) : rowv[a_row];
    const float* agp = (MODE == 1) ? agg + (size_t)rv * HID : nullptr;
    const unsigned short* hp = (MODE == 1) ? hcur + (size_t)((r0 + a_row) ^ 1) * HID : nullptr;
    const float* xp  = (MODE != 1) ? xin + (size_t)rv * NF : nullptr;
    const float* ap  = (MODE == 0) ? aux + (size_t)(r0 + a_row) * EF - NF
                     : (MODE == 2) ? aux + (size_t)rv * HID - NF : nullptr;
    const bool node_ok = (MODE != 2) || (rv < NN);

    #pragma unroll
    for (int b0 = 0; b0 < SITER; b0 += 8) {
      float4 av[8]; ushort4 hv[8]; float fv[8][4];
      #pragma unroll
      for (int j = 0; j < 8; ++j) {
        const int it = b0 + j;
        if (it >= SITER) continue;
        const bool ok = (t + it * THR) < PIECES;
        const int k = ((a_c + 4 * it) << 3) + a_h4;
        if (MODE == 1) {
          av[j] = make_float4(0.f, 0.f, 0.f, 0.f);
          hv[j] = make_ushort4(0, 0, 0, 0);
          if (ok && k < HID) {
            av[j] = *(const float4*)(agp + k);
            hv[j] = *(const ushort4*)(hp + k);
          }
        } else {
          #pragma unroll
          for (int q = 0; q < 4; ++q) {
            const int kk = k + q;
            float f = 0.f;
            if (ok && node_ok) {
              if (kk < NF) f = xp[kk];
              else if (kk < KEFF) f = ap[kk];
            }
            fv[j][q] = f;
          }
        }
      }
      #pragma unroll
      for (int j = 0; j < 8; ++j) {
        const int it = b0 + j;
        if (it >= SITER) continue;
        if ((t + it * THR) >= PIECES) continue;
        ushort4 o;
        if (MODE == 1) {
          o.x = f2bf(av[j].x - bf2f(hv[j].x));
          o.y = f2bf(av[j].y - bf2f(hv[j].y));
          o.z = f2bf(av[j].z - bf2f(hv[j].z));
          o.w = f2bf(av[j].w - bf2f(hv[j].w));
        } else {
          o.x = f2bf(fv[j][0]); o.y = f2bf(fv[j][1]);
          o.z = f2bf(fv[j][2]); o.w = f2bf(fv[j][3]);
        }
        *(ushort4*)(S_lds + (size_t)(t + it * THR) * 4) = o;
      }
    }
  }
  __syncthreads();

  f32x4 acc[5][2];
  #pragma unroll
  for (int ni = 0; ni < 5; ++ni)
    #pragma unroll
    for (int i = 0; i < 2; ++i) acc[ni][i] = (f32x4)0.f;

  // ---- barrier-free k-loop (R8 shape: ntc-guarded, compiler-scheduled) ----
  #pragma unroll
  for (int kt = 0; kt < KTILES; ++kt) {
    int kg = kt * 4 + lg;
    if (kt * 4 + 3 >= NKG_A) kg = (kg < NKG_A) ? kg : 0;   // compile-time guard on kt
    bf16x8 ef[2];
    #pragma unroll
    for (int i = 0; i < 2; ++i) {
      const int et = etg * 2 + i;
      ef[i] = *(const bf16x8*)(S_lds + (size_t)((kg * 64 + et * 16 + lr)) * 8);
    }
    const unsigned short* wk = wbt + (((size_t)kt * WGRAN + nt0 * 64 + l) << 3);
    #pragma unroll
    for (int ni = 0; ni < 5; ++ni) {
      if (ni < ntc) {
        const bf16x8 wf = *(const bf16x8*)(wk + ((size_t)ni << 9));
        #pragma unroll
        for (int i = 0; i < 2; ++i)
          acc[ni][i] = __builtin_amdgcn_mfma_f32_16x16x32_bf16(wf, ef[i], acc[ni][i], 0, 0, 0);
      }
    }
  }

  if (MODE == 2) {
    // direct scattered epilogue (small: 157 blocks, 12 MB out)
    #pragma unroll
    for (int ni = 0; ni < 5; ++ni) {
      if (ni >= ntc) continue;
      const int n = ((nt0 + ni) << 4) + (lg << 2);
      if (n >= HID) continue;
      const float4 bv = *(const float4*)(bias + n);
      #pragma unroll
      for (int i = 0; i < 2; ++i) {
        const int node = r0 + ((etg * 2 + i) << 4) + lr;
        if (node >= NN) continue;
        float v0 = fmaxf(acc[ni][i][0] + bv.x, 0.f);
        float v1 = fmaxf(acc[ni][i][1] + bv.y, 0.f);
        float v2 = fmaxf(acc[ni][i][2] + bv.z, 0.f);
        float v3 = fmaxf(acc[ni][i][3] + bv.w, 0.f);
        *(float4*)(outF + (size_t)node * HID + n) = make_float4(v0, v1, v2, v3);
      }
    }
    return;
  }

  // ---- stage C tile (acc + bias, pre-relu) into LDS (reuses S_lds) ----
  __syncthreads();   // all fragment reads done before overwrite
  #pragma unroll
  for (int ni = 0; ni < 5; ++ni) {
    if (ni >= ntc) continue;
    const int n = ((nt0 + ni) << 4) + (lg << 2);
    float4 bv = make_float4(0.f, 0.f, 0.f, 0.f);
    if (n < HID) bv = *(const float4*)(bias + n);
    #pragma unroll
    for (int i = 0; i < 2; ++i) {
      const int row = ((etg * 2 + i) << 4) + lr;
      ushort4 o;
      o.x = f2bf(acc[ni][i][0] + bv.x);
      o.y = f2bf(acc[ni][i][1] + bv.y);
      o.z = f2bf(acc[ni][i][2] + bv.z);
      o.w = f2bf(acc[ni][i][3] + bv.w);
      if (n + 4 <= CSTRIDE) *(ushort4*)(S_lds + row * CSTRIDE + n) = o;
    }
  }
  __syncthreads();

  // ---- linear write-out, batched loads: 64 rows x 75 ushort4-chunks ----
  {
    const size_t base = (size_t)r0 * HID;
    constexpr int WITER = (BR * 75 + THR - 1) / THR;   // 10
    #pragma unroll
    for (int b0 = 0; b0 < WITER; b0 += 8) {
      ushort4 cv[8], hz[8];
      #pragma unroll
      for (int j = 0; j < 8; ++j) {
        const int it = b0 + j;
        if (it >= WITER) continue;
        const int s = t + it * THR;
        if (s >= BR * 75) continue;
        const int row = s / 75;
        const int idx = s - row * 75;
        cv[j] = *(const ushort4*)(S_lds + row * CSTRIDE + (idx << 2));
        if (MODE == 1) hz[j] = *(const ushort4*)(h0 + base + (size_t)row * HID + (idx << 2));
      }
      #pragma unroll
      for (int j = 0; j < 8; ++j) {
        const int it = b0 + j;
        if (it >= WITER) continue;
        const int s = t + it * THR;
        if (s >= BR * 75) continue;
        const int row = s / 75;
        const int idx = s - row * 75;
        float v0 = bf2f(cv[j].x), v1 = bf2f(cv[j].y), v2 = bf2f(cv[j].z), v3 = bf2f(cv[j].w);
        if (MODE == 1) {
          v0 += bf2f(hz[j].x); v1 += bf2f(hz[j].y);
          v2 += bf2f(hz[j].z); v3 += bf2f(hz[j].w);
        }
        ushort4 o;
        o.x = f2bf(fmaxf(v0, 0.f)); o.y = f2bf(fmaxf(v1, 0.f));
        o.z = f2bf(fmaxf(v2, 0.f)); o.w = f2bf(fmaxf(v3, 0.f));
        const size_t off = base + (size_t)row * HID + (idx << 2);
        *(ushort4*)(outA + off) = o;
        if (MODE == 0) *(ushort4*)(outB + off) = o;
      }
    }
  }
}

// ---------------- output init + fused dot/pool ----------------
__global__ void init_out_kernel(float* __restrict__ out, const float* __restrict__ b_ffn) {
  int t = threadIdx.x;
  if (t < NG) out[t] = b_ffn[0];
}

__global__ void dotpool_kernel(const float* __restrict__ hn, const float* __restrict__ wffn,
                               const int* __restrict__ batch, float* __restrict__ out) {
  const int wave = threadIdx.x >> 6, lane = threadIdx.x & 63;
  const int v = blockIdx.x * 4 + wave;
  if (v >= NN) return;
  float s = 0.f;
  for (int j = lane; j < HID; j += 64) s += hn[(size_t)v * HID + j] * wffn[j];
  #pragma unroll
  for (int off = 32; off > 0; off >>= 1) s += __shfl_down(s, off, 64);
  if (lane == 0) atomicAdd(&out[batch[v]], s);
}

// ---------------- launch ----------------
extern "C" void kernel_launch(void* const* d_in, const int* in_sizes, int n_in,
                              void* d_out, int out_size, void* d_ws, size_t ws_size,
                              hipStream_t stream) {
  const float* x     = (const float*)d_in[0];
  const int*   eidx  = (const int*)d_in[1];
  const float* eattr = (const float*)d_in[2];
  const int*   batch = (const int*)d_in[3];
  const float* W_ei  = (const float*)d_in[4];
  const float* b_ei  = (const float*)d_in[5];
  const float* Ws    = (const float*)d_in[6];
  const float* bs    = (const float*)d_in[7];
  const float* W_en  = (const float*)d_in[8];
  const float* b_en  = (const float*)d_in[9];
  const float* W_ffn = (const float*)d_in[10];
  const float* b_ffn = (const float*)d_in[11];
  float* out = (float*)d_out;

  const int* row  = eidx;
  const int* colv = eidx + NE;

  // workspace layout (~218 MB)
  char* ws = (char*)d_ws;
  unsigned short* h0 = (unsigned short*)(ws + 0);              //  96,000,000 B
  unsigned short* h  = (unsigned short*)(ws + 96000000ull);    //  96,000,000 B
  float* abuf        = (float*)(ws + 192000000ull);            //  12,000,000 B
  float* hn          = (float*)(ws + 204000000ull);            //  12,000,000 B
  int* indptr        = (int*)(ws + 216000000ull);              //      40,004 B
  int* cnt           = (int*)(ws + 216040192ull);              //      40,000 B
  int* eids          = (int*)(ws + 216080384ull);              //     640,000 B
  unsigned short* wbt0 = (unsigned short*)(ws + 216720384ull); //      97,280 B (5 kt)
  unsigned short* wbtC = (unsigned short*)(ws + 216817664ull); //  3x 194,560 B (10 kt)
  unsigned short* wbtN = (unsigned short*)(ws + 217401344ull); //     272,384 B (14 kt)

  // CSR over col (scatter restores cnt to 0)
  zero_kernel<<<(NN + 255) / 256, 256, 0, stream>>>(cnt, NN);
  hist_kernel<<<NE / 256, 256, 0, stream>>>(colv, cnt);
  scan_kernel<<<1, 1024, 0, stream>>>(cnt, indptr);
  scatter_kernel<<<NE / 256, 256, 0, stream>>>(colv, indptr, cnt, eids);

  // weight pre-transposes (bf16, MFMA fragment order, zero-padded tails)
  wtrans_kernel<<<5 * NT, 64, 0, stream>>>(W_ei, NF + EF, wbt0);
  for (int lyr = 0; lyr < 3; ++lyr)
    wtrans_kernel<<<10 * NT, 64, 0, stream>>>(Ws + (size_t)lyr * HID * HID, HID,
                                              wbtC + (size_t)lyr * 10 * WGRAN * 8);
  wtrans_kernel<<<14 * NT, 64, 0, stream>>>(W_en, NF + HID, wbtN);

  // h0 = relu([x[row]|ea] @ W_ei + b_ei); h = h0
  gemm_kernel<0, 5><<<NE / BR, THR, 0, stream>>>(
      x, row, eattr, nullptr, nullptr, nullptr, wbt0, b_ei, h0, h, nullptr);

  for (int lyr = 0; lyr < 3; ++lyr) {
    segsum_kernel<<<NN, 256, 0, stream>>>(h, indptr, eids, abuf);
    gemm_kernel<1, 10><<<NE / BR, THR, 0, stream>>>(
        nullptr, row, nullptr, abuf, h, h0,
        wbtC + (size_t)lyr * 10 * WGRAN * 8, bs + (size_t)lyr * HID,
        h, nullptr, nullptr);                 // in-place update of h
  }

  // s = segsum(h, col); hn = relu([x|s] @ W_en + b_en)
  segsum_kernel<<<NN, 256, 0, stream>>>(h, indptr, eids, abuf);
  gemm_kernel<2, 14><<<(NN + BR - 1) / BR, THR, 0, stream>>>(
      x, nullptr, abuf, nullptr, nullptr, nullptr, wbtN, b_en,
      nullptr, nullptr, hn);

  // out[g] = b_ffn + sum_{batch[v]=g} hn[v] . W_ffn
  init_out_kernel<<<1, 64, 0, stream>>>(out, b_ffn);
  dotpool_kernel<<<NN / 4, 256, 0, stream>>>(hn, W_ffn, batch, out);
}

// Round 12
// 626.031 us; speedup vs baseline: 1.1106x; 1.1106x over previous
//
#include <hip/hip_runtime.h>
#include <stdint.h>

#define NN 10000      // nodes
#define NE 160000     // edges (paired: e and e^1 are fwd/rev)
#define HID 300
#define NF 133
#define EF 14
#define NG 64

#define BR 32         // edge rows per GEMM block (pairs stay inside block)
#define NT 19         // n-tiles of 16 (304 padded cols)
#define WGRAN (NT*64) // 1216 16B-granules of W per k-step
#define CSTRIDE 308   // LDS C-tile column stride (ushorts)

typedef __bf16 bf16x8 __attribute__((ext_vector_type(8)));
typedef float f32x4 __attribute__((ext_vector_type(4)));

union GR { bf16x8 v; unsigned short s[8]; uint4 u; };

__device__ __forceinline__ float bf2f(unsigned short u) {
  union { unsigned int i; float f; } x; x.i = ((unsigned int)u) << 16; return x.f;
}
__device__ __forceinline__ unsigned short f2bf(float f) {
  union { float f; unsigned int i; } x; x.f = f;
  unsigned int r = x.i + 0x7fffu + ((x.i >> 16) & 1u);
  return (unsigned short)(r >> 16);
}

// ---------------- small utilities ----------------
__global__ void zero_kernel(int* __restrict__ p, int n) {
  int i = blockIdx.x * 256 + threadIdx.x;
  if (i < n) p[i] = 0;
}

// ---------------- CSR build over col ----------------
__global__ void hist_kernel(const int* __restrict__ col, int* __restrict__ cnt) {
  int e = blockIdx.x * 256 + threadIdx.x;
  if (e < NE) atomicAdd(&cnt[col[e]], 1);
}

__global__ void scan_kernel(const int* __restrict__ cnt, int* __restrict__ indptr) {
  __shared__ int part[1024];
  int t = threadIdx.x;
  int base = t * 10;
  int loc[10];
  int s = 0;
  #pragma unroll
  for (int i = 0; i < 10; ++i) {
    int n = base + i;
    int v = (n < NN) ? cnt[n] : 0;
    loc[i] = s; s += v;
  }
  part[t] = s;
  __syncthreads();
  for (int off = 1; off < 1024; off <<= 1) {
    int v = part[t];
    int u = (t >= off) ? part[t - off] : 0;
    __syncthreads();
    part[t] = v + u;
    __syncthreads();
  }
  int pre = (t == 0) ? 0 : part[t - 1];
  #pragma unroll
  for (int i = 0; i < 10; ++i) {
    int n = base + i;
    if (n <= NN) indptr[n] = pre + loc[i];
  }
}

// consumes cnt back to zero (self-restoring across graph replays)
__global__ void scatter_kernel(const int* __restrict__ col, const int* __restrict__ indptr,
                               int* __restrict__ cnt, int* __restrict__ eids) {
  int e = blockIdx.x * 256 + threadIdx.x;
  if (e < NE) {
    int v = col[e];
    int p = atomicSub(&cnt[v], 1) - 1;
    eids[indptr[v] + p] = e;
  }
}

// ---- segment_sum(h[bf16], col) -> a[f32]: vectorized, 3 row-slots/block ----
__global__ __launch_bounds__(256)
void segsum_kernel(const unsigned short* __restrict__ h,
                   const int* __restrict__ indptr, const int* __restrict__ eids,
                   float* __restrict__ a) {
  __shared__ float4 part[3][76];
  const int v = blockIdx.x;
  const int t = threadIdx.x;
  const int beg = indptr[v], end = indptr[v + 1];
  if (t < 225) {
    const int g = t % 75;          // ushort4 granule (cols 4g..4g+3)
    const int s = t / 75;          // row slot 0..2
    const int c4 = g << 2;
    float a0 = 0.f, a1 = 0.f, a2 = 0.f, a3 = 0.f;
    float b0 = 0.f, b1 = 0.f, b2 = 0.f, b3 = 0.f;
    int p = beg + s;
    for (; p + 6 <= end; p += 6) {       // 2 rows per iteration (stride 3)
      const int e0 = eids[p], e1 = eids[p + 3];
      const ushort4 h0v = *(const ushort4*)(h + (size_t)e0 * HID + c4);
      const ushort4 h1v = *(const ushort4*)(h + (size_t)e1 * HID + c4);
      a0 += bf2f(h0v.x); a1 += bf2f(h0v.y); a2 += bf2f(h0v.z); a3 += bf2f(h0v.w);
      b0 += bf2f(h1v.x); b1 += bf2f(h1v.y); b2 += bf2f(h1v.z); b3 += bf2f(h1v.w);
    }
    if (p < end) {                       // tail step 1
      const int e0 = eids[p];
      const ushort4 h0v = *(const ushort4*)(h + (size_t)e0 * HID + c4);
      a0 += bf2f(h0v.x); a1 += bf2f(h0v.y); a2 += bf2f(h0v.z); a3 += bf2f(h0v.w);
      p += 3;
    }
    if (p < end) {                       // tail step 2
      const int e1 = eids[p];
      const ushort4 h1v = *(const ushort4*)(h + (size_t)e1 * HID + c4);
      b0 += bf2f(h1v.x); b1 += bf2f(h1v.y); b2 += bf2f(h1v.z); b3 += bf2f(h1v.w);
    }
    part[s][g] = make_float4(a0 + b0, a1 + b1, a2 + b2, a3 + b3);
  }
  __syncthreads();
  if (t < 75) {
    const float4 p0 = part[0][t], p1 = part[1][t], p2 = part[2][t];
    *(float4*)(a + (size_t)v * HID + (t << 2)) =
        make_float4(p0.x + p1.x + p2.x, p0.y + p1.y + p2.y,
                    p0.z + p1.z + p2.z, p0.w + p1.w + p2.w);
  }
}

// ---------------- weight pre-transpose into MFMA fragment order -------------
// dst granule (kt,nt,lane l) holds W[kt*32 + (l>>4)*8 + i][nt*16 + (l&15)], i=0..7
__global__ void wtrans_kernel(const float* __restrict__ W, int K,
                              unsigned short* __restrict__ dst) {
  const int b = blockIdx.x;          // kt*NT + nt
  const int l = threadIdx.x;         // 0..63
  const int kt = b / NT, nt = b - kt * NT;
  const int k0 = kt * 32 + ((l >> 4) << 3);
  const int n  = (nt << 4) + (l & 15);
  GR g;
  #pragma unroll
  for (int i = 0; i < 8; ++i) {
    const int k = k0 + i;
    float f = (k < K && n < HID) ? W[(size_t)k * HID + n] : 0.f;
    g.s[i] = f2bf(f);
  }
  *(uint4*)(dst + ((size_t)(b * 64 + l) << 3)) = g.u;
}

// ---------------- MFMA GEMM: 32-row blocks, 5 independent blocks/CU ---------
// Per block: 32 rows x 304 cols, 4 waves (wave = n-tile group, 5 nt each;
// wave 3 has 4). acc[5][2] = 40 AGPR; batch-4 staging; launch_bounds(256,5)
// -> 5 blocks/CU, each with its own phase position (R11 showed lockstep
// occupancy doesn't help; independent block phases is the lever).
// A staged ONCE into LDS in fragment order [kg][row]x16B.
// MODE 0: edge_init  h0 = relu([x[row]|ea] @ W + b)
// MODE 1: conv       out[e] = relu((a[row[e]] - bf(hcur[e^1])) @ W + b + bf(h0[e]))
//                    layer 0: hcur=h0, out=h (no alias); layers 1-2: in place on h
// MODE 2: node MLP   hn = relu([x|s] @ W + b)  (f32 out)
template<int MODE, int KTILES>
__global__ __launch_bounds__(256, 5)
void gemm_kernel(const float* __restrict__ xin,
                 const int* __restrict__ rowidx,
                 const float* __restrict__ aux,        // MODE0: edge_attr ; MODE2: s
                 const float* __restrict__ agg,        // MODE1: a
                 const unsigned short* hcur,           // MODE1 in (may alias outA)
                 const unsigned short* __restrict__ h0,
                 const unsigned short* __restrict__ wbt,  // fragment-ordered bf16 W^T
                 const float* __restrict__ bias,
                 unsigned short* outA,
                 float* __restrict__ outF)
{
  constexpr int KEFF = (MODE == 0) ? (NF + EF) : ((MODE == 1) ? HID : (NF + HID));
  constexpr int NKG_A = (KEFF + 7) / 8;           // staged 16B k-granules per row
  constexpr int STAGE_USH = NKG_A * BR * 8;       // staged-A ushorts
  constexpr int PIECES = STAGE_USH / 4;           // ushort4 pieces
  constexpr int SITER = (PIECES + 255) / 256;
  constexpr int LDS_USH = (MODE == 2) ? STAGE_USH
                        : ((STAGE_USH > BR * CSTRIDE) ? STAGE_USH : BR * CSTRIDE);
  __shared__ unsigned short S_lds[LDS_USH];       // A-stage, then C-tile
  __shared__ int rowv[BR];

  const int t = threadIdx.x;
  const int l = t & 63;
  const int wave = t >> 6;           // 0..3 -> n-tile group
  const int lr = l & 15;             // row within 16-tile
  const int lg = l >> 4;             // k-granule slot / output col-group
  const int r0 = blockIdx.x * BR;
  const int nt0 = wave * 5;
  const int ntc = (wave == 3) ? 4 : 5;

  if (MODE != 2 && t < BR) rowv[t] = rowidx[r0 + t];
  __syncthreads();

  // ---- stage A once; piece s = t + 256*it ----
  // granule g = s>>1: row=(t>>1)&31 (fixed/thread), kg=(t>>6)+4*it, half=t&1
  {
    const int a_row = (t >> 1) & 31;
    const int a_c   = t >> 6;        // 0..3
    const int a_h4  = (t & 1) << 2;
    const int rv    = (MODE == 2) ? (r0 + a_row) : rowv[a_row];
    const float* agp = (MODE == 1) ? agg + (size_t)rv * HID : nullptr;
    const unsigned short* hp = (MODE == 1) ? hcur + (size_t)((r0 + a_row) ^ 1) * HID : nullptr;
    const float* xp  = (MODE != 1) ? xin + (size_t)rv * NF : nullptr;
    const float* ap  = (MODE == 0) ? aux + (size_t)(r0 + a_row) * EF - NF
                     : (MODE == 2) ? aux + (size_t)rv * HID - NF : nullptr;
    const bool node_ok = (MODE != 2) || (rv < NN);

    #pragma unroll
    for (int b0 = 0; b0 < SITER; b0 += 4) {
      float4 av[4]; ushort4 hv[4]; float fv[4][4];
      #pragma unroll
      for (int j = 0; j < 4; ++j) {
        const int it = b0 + j;
        if (it >= SITER) continue;
        const bool ok = (t + (it << 8)) < PIECES;
        const int k = ((a_c + 4 * it) << 3) + a_h4;
        if (MODE == 1) {
          av[j] = make_float4(0.f, 0.f, 0.f, 0.f);
          hv[j] = make_ushort4(0, 0, 0, 0);
          if (ok && k < HID) {
            av[j] = *(const float4*)(agp + k);
            hv[j] = *(const ushort4*)(hp + k);
          }
        } else {
          #pragma unroll
          for (int q = 0; q < 4; ++q) {
            const int kk = k + q;
            float f = 0.f;
            if (ok && node_ok) {
              if (kk < NF) f = xp[kk];
              else if (kk < KEFF) f = ap[kk];
            }
            fv[j][q] = f;
          }
        }
      }
      #pragma unroll
      for (int j = 0; j < 4; ++j) {
        const int it = b0 + j;
        if (it >= SITER) continue;
        if ((t + (it << 8)) >= PIECES) continue;
        ushort4 o;
        if (MODE == 1) {
          o.x = f2bf(av[j].x - bf2f(hv[j].x));
          o.y = f2bf(av[j].y - bf2f(hv[j].y));
          o.z = f2bf(av[j].z - bf2f(hv[j].z));
          o.w = f2bf(av[j].w - bf2f(hv[j].w));
        } else {
          o.x = f2bf(fv[j][0]); o.y = f2bf(fv[j][1]);
          o.z = f2bf(fv[j][2]); o.w = f2bf(fv[j][3]);
        }
        *(ushort4*)(S_lds + (size_t)(t + (it << 8)) * 4) = o;
      }
    }
  }
  __syncthreads();

  f32x4 acc[5][2];
  #pragma unroll
  for (int ni = 0; ni < 5; ++ni)
    #pragma unroll
    for (int i = 0; i < 2; ++i) acc[ni][i] = (f32x4)0.f;

  // ---- barrier-free k-loop (ntc-guarded; compiler-scheduled) ----
  #pragma unroll
  for (int kt = 0; kt < KTILES; ++kt) {
    int kg = kt * 4 + lg;
    if (kt * 4 + 3 >= NKG_A) kg = (kg < NKG_A) ? kg : 0;   // compile-time guard on kt
    bf16x8 ef[2];
    #pragma unroll
    for (int i = 0; i < 2; ++i)
      ef[i] = *(const bf16x8*)(S_lds + (size_t)((kg * BR + i * 16 + lr)) * 8);
    const unsigned short* wk = wbt + (((size_t)kt * WGRAN + nt0 * 64 + l) << 3);
    #pragma unroll
    for (int ni = 0; ni < 5; ++ni) {
      if (ni < ntc) {
        const bf16x8 wf = *(const bf16x8*)(wk + ((size_t)ni << 9));
        #pragma unroll
        for (int i = 0; i < 2; ++i)
          acc[ni][i] = __builtin_amdgcn_mfma_f32_16x16x32_bf16(wf, ef[i], acc[ni][i], 0, 0, 0);
      }
    }
  }

  if (MODE == 2) {
    // direct scattered epilogue (small: 313 blocks, 12 MB out)
    #pragma unroll
    for (int ni = 0; ni < 5; ++ni) {
      if (ni >= ntc) continue;
      const int n = ((nt0 + ni) << 4) + (lg << 2);
      if (n >= HID) continue;
      const float4 bv = *(const float4*)(bias + n);
      #pragma unroll
      for (int i = 0; i < 2; ++i) {
        const int node = r0 + (i << 4) + lr;
        if (node >= NN) continue;
        float v0 = fmaxf(acc[ni][i][0] + bv.x, 0.f);
        float v1 = fmaxf(acc[ni][i][1] + bv.y, 0.f);
        float v2 = fmaxf(acc[ni][i][2] + bv.z, 0.f);
        float v3 = fmaxf(acc[ni][i][3] + bv.w, 0.f);
        *(float4*)(outF + (size_t)node * HID + n) = make_float4(v0, v1, v2, v3);
      }
    }
    return;
  }

  // ---- stage C tile (acc + bias, pre-relu) into LDS (reuses S_lds) ----
  __syncthreads();   // all fragment reads done before overwrite
  #pragma unroll
  for (int ni = 0; ni < 5; ++ni) {
    if (ni >= ntc) continue;
    const int n = ((nt0 + ni) << 4) + (lg << 2);
    float4 bv = make_float4(0.f, 0.f, 0.f, 0.f);
    if (n < HID) bv = *(const float4*)(bias + n);
    #pragma unroll
    for (int i = 0; i < 2; ++i) {
      const int row = (i << 4) + lr;
      ushort4 o;
      o.x = f2bf(acc[ni][i][0] + bv.x);
      o.y = f2bf(acc[ni][i][1] + bv.y);
      o.z = f2bf(acc[ni][i][2] + bv.z);
      o.w = f2bf(acc[ni][i][3] + bv.w);
      if (n + 4 <= CSTRIDE) *(ushort4*)(S_lds + row * CSTRIDE + n) = o;
    }
  }
  __syncthreads();

  // ---- linear write-out, batched loads: 32 rows x 75 ushort4-chunks ----
  {
    const size_t base = (size_t)r0 * HID;
    constexpr int WITER = (BR * 75 + 255) / 256;   // 10
    #pragma unroll
    for (int b0 = 0; b0 < WITER; b0 += 5) {
      ushort4 cv[5], hz[5];
      #pragma unroll
      for (int j = 0; j < 5; ++j) {
        const int it = b0 + j;
        if (it >= WITER) continue;
        const int s = t + (it << 8);
        if (s >= BR * 75) continue;
        const int row = s / 75;
        const int idx = s - row * 75;
        cv[j] = *(const ushort4*)(S_lds + row * CSTRIDE + (idx << 2));
        if (MODE == 1) hz[j] = *(const ushort4*)(h0 + base + (size_t)row * HID + (idx << 2));
      }
      #pragma unroll
      for (int j = 0; j < 5; ++j) {
        const int it = b0 + j;
        if (it >= WITER) continue;
        const int s = t + (it << 8);
        if (s >= BR * 75) continue;
        const int row = s / 75;
        const int idx = s - row * 75;
        float v0 = bf2f(cv[j].x), v1 = bf2f(cv[j].y), v2 = bf2f(cv[j].z), v3 = bf2f(cv[j].w);
        if (MODE == 1) {
          v0 += bf2f(hz[j].x); v1 += bf2f(hz[j].y);
          v2 += bf2f(hz[j].z); v3 += bf2f(hz[j].w);
        }
        ushort4 o;
        o.x = f2bf(fmaxf(v0, 0.f)); o.y = f2bf(fmaxf(v1, 0.f));
        o.z = f2bf(fmaxf(v2, 0.f)); o.w = f2bf(fmaxf(v3, 0.f));
        const size_t off = base + (size_t)row * HID + (idx << 2);
        *(ushort4*)(outA + off) = o;
      }
    }
  }
}

// ---------------- output init + fused dot/pool ----------------
__global__ void init_out_kernel(float* __restrict__ out, const float* __restrict__ b_ffn) {
  int t = threadIdx.x;
  if (t < NG) out[t] = b_ffn[0];
}

__global__ void dotpool_kernel(const float* __restrict__ hn, const float* __restrict__ wffn,
                               const int* __restrict__ batch, float* __restrict__ out) {
  const int wave = threadIdx.x >> 6, lane = threadIdx.x & 63;
  const int v = blockIdx.x * 4 + wave;
  if (v >= NN) return;
  float s = 0.f;
  for (int j = lane; j < HID; j += 64) s += hn[(size_t)v * HID + j] * wffn[j];
  #pragma unroll
  for (int off = 32; off > 0; off >>= 1) s += __shfl_down(s, off, 64);
  if (lane == 0) atomicAdd(&out[batch[v]], s);
}

// ---------------- launch ----------------
extern "C" void kernel_launch(void* const* d_in, const int* in_sizes, int n_in,
                              void* d_out, int out_size, void* d_ws, size_t ws_size,
                              hipStream_t stream) {
  const float* x     = (const float*)d_in[0];
  const int*   eidx  = (const int*)d_in[1];
  const float* eattr = (const float*)d_in[2];
  const int*   batch = (const int*)d_in[3];
  const float* W_ei  = (const float*)d_in[4];
  const float* b_ei  = (const float*)d_in[5];
  const float* Ws    = (const float*)d_in[6];
  const float* bs    = (const float*)d_in[7];
  const float* W_en  = (const float*)d_in[8];
  const float* b_en  = (const float*)d_in[9];
  const float* W_ffn = (const float*)d_in[10];
  const float* b_ffn = (const float*)d_in[11];
  float* out = (float*)d_out;

  const int* row  = eidx;
  const int* colv = eidx + NE;

  // workspace layout (~218 MB)
  char* ws = (char*)d_ws;
  unsigned short* h0 = (unsigned short*)(ws + 0);              //  96,000,000 B
  unsigned short* h  = (unsigned short*)(ws + 96000000ull);    //  96,000,000 B
  float* abuf        = (float*)(ws + 192000000ull);            //  12,000,000 B
  float* hn          = (float*)(ws + 204000000ull);            //  12,000,000 B
  int* indptr        = (int*)(ws + 216000000ull);              //      40,004 B
  int* cnt           = (int*)(ws + 216040192ull);              //      40,000 B
  int* eids          = (int*)(ws + 216080384ull);              //     640,000 B
  unsigned short* wbt0 = (unsigned short*)(ws + 216720384ull); //      97,280 B (5 kt)
  unsigned short* wbtC = (unsigned short*)(ws + 216817664ull); //  3x 194,560 B (10 kt)
  unsigned short* wbtN = (unsigned short*)(ws + 217401344ull); //     272,384 B (14 kt)

  // CSR over col (scatter restores cnt to 0)
  zero_kernel<<<(NN + 255) / 256, 256, 0, stream>>>(cnt, NN);
  hist_kernel<<<NE / 256, 256, 0, stream>>>(colv, cnt);
  scan_kernel<<<1, 1024, 0, stream>>>(cnt, indptr);
  scatter_kernel<<<NE / 256, 256, 0, stream>>>(colv, indptr, cnt, eids);

  // weight pre-transposes (bf16, MFMA fragment order, zero-padded tails)
  wtrans_kernel<<<5 * NT, 64, 0, stream>>>(W_ei, NF + EF, wbt0);
  for (int lyr = 0; lyr < 3; ++lyr)
    wtrans_kernel<<<10 * NT, 64, 0, stream>>>(Ws + (size_t)lyr * HID * HID, HID,
                                              wbtC + (size_t)lyr * 10 * WGRAN * 8);
  wtrans_kernel<<<14 * NT, 64, 0, stream>>>(W_en, NF + HID, wbtN);

  // h0 = relu([x[row]|ea] @ W_ei + b_ei)   (no duplicate h copy: layer 0
  // reads hcur=h0 directly and writes h)
  gemm_kernel<0, 5><<<NE / BR, 256, 0, stream>>>(
      x, row, eattr, nullptr, nullptr, nullptr, wbt0, b_ei, h0, nullptr);

  // layer 0: a = segsum(h0); h = relu((a[row]-h0[e^1])@W0 + b0 + h0)
  segsum_kernel<<<NN, 256, 0, stream>>>(h0, indptr, eids, abuf);
  gemm_kernel<1, 10><<<NE / BR, 256, 0, stream>>>(
      nullptr, row, nullptr, abuf, h0, h0, wbtC, bs, h, nullptr);

  // layers 1,2: in-place on h
  for (int lyr = 1; lyr < 3; ++lyr) {
    segsum_kernel<<<NN, 256, 0, stream>>>(h, indptr, eids, abuf);
    gemm_kernel<1, 10><<<NE / BR, 256, 0, stream>>>(
        nullptr, row, nullptr, abuf, h, h0,
        wbtC + (size_t)lyr * 10 * WGRAN * 8, bs + (size_t)lyr * HID,
        h, nullptr);
  }

  // s = segsum(h, col); hn = relu([x|s] @ W_en + b_en)
  segsum_kernel<<<NN, 256, 0, stream>>>(h, indptr, eids, abuf);
  gemm_kernel<2, 14><<<(NN + BR - 1) / BR, 256, 0, stream>>>(
      x, nullptr, abuf, nullptr, nullptr, nullptr, wbtN, b_en,
      nullptr, hn);

  // out[g] = b_ffn + sum_{batch[v]=g} hn[v] . W_ffn
  init_out_kernel<<<1, 64, 0, stream>>>(out, b_ffn);
  dotpool_kernel<<<NN / 4, 256, 0, stream>>>(hn, W_ffn, batch, out);
}

// Round 13
// 592.514 us; speedup vs baseline: 1.1734x; 1.0566x over previous
//
#include <hip/hip_runtime.h>
#include <stdint.h>

#define NN 10000      // nodes
#define NE 160000     // edges (paired: e and e^1 are fwd/rev)
#define HID 300
#define PH 304        // padded row stride (bf16 rows 608B, f32 rows 1216B; 16B-aligned)
#define NF 133
#define EF 14
#define NG 64

#define BR 32         // edge rows per GEMM block (pairs stay inside block)
#define NT 19         // n-tiles of 16 (304 padded cols)
#define WGRAN (NT*64) // 1216 16B-granules of W per k-step
#define CSTRIDE 304   // LDS C-tile column stride (ushorts)

typedef __bf16 bf16x8 __attribute__((ext_vector_type(8)));
typedef float f32x4 __attribute__((ext_vector_type(4)));

union GR { bf16x8 v; unsigned short s[8]; uint4 u; };

__device__ __forceinline__ float bf2f(unsigned short u) {
  union { unsigned int i; float f; } x; x.i = ((unsigned int)u) << 16; return x.f;
}
__device__ __forceinline__ unsigned short f2bf(float f) {
  union { float f; unsigned int i; } x; x.f = f;
  unsigned int r = x.i + 0x7fffu + ((x.i >> 16) & 1u);
  return (unsigned short)(r >> 16);
}

// ---------------- small utilities ----------------
__global__ void zero_kernel(int* __restrict__ p, int n) {
  int i = blockIdx.x * 256 + threadIdx.x;
  if (i < n) p[i] = 0;
}

// ---------------- CSR build over col ----------------
__global__ void hist_kernel(const int* __restrict__ col, int* __restrict__ cnt) {
  int e = blockIdx.x * 256 + threadIdx.x;
  if (e < NE) atomicAdd(&cnt[col[e]], 1);
}

__global__ void scan_kernel(const int* __restrict__ cnt, int* __restrict__ indptr) {
  __shared__ int part[1024];
  int t = threadIdx.x;
  int base = t * 10;
  int loc[10];
  int s = 0;
  #pragma unroll
  for (int i = 0; i < 10; ++i) {
    int n = base + i;
    int v = (n < NN) ? cnt[n] : 0;
    loc[i] = s; s += v;
  }
  part[t] = s;
  __syncthreads();
  for (int off = 1; off < 1024; off <<= 1) {
    int v = part[t];
    int u = (t >= off) ? part[t - off] : 0;
    __syncthreads();
    part[t] = v + u;
    __syncthreads();
  }
  int pre = (t == 0) ? 0 : part[t - 1];
  #pragma unroll
  for (int i = 0; i < 10; ++i) {
    int n = base + i;
    if (n <= NN) indptr[n] = pre + loc[i];
  }
}

// consumes cnt back to zero (self-restoring across graph replays)
__global__ void scatter_kernel(const int* __restrict__ col, const int* __restrict__ indptr,
                               int* __restrict__ cnt, int* __restrict__ eids) {
  int e = blockIdx.x * 256 + threadIdx.x;
  if (e < NE) {
    int v = col[e];
    int p = atomicSub(&cnt[v], 1) - 1;
    eids[indptr[v] + p] = e;
  }
}

// ---- segment_sum(h[bf16,PH], col) -> a[f32,PH]: 16B granules, 6 slots ------
// Slot s owns positions beg+s, beg+s+6, ...; pair-unrolled; two-step tail.
__global__ __launch_bounds__(256)
void segsum_kernel(const unsigned short* __restrict__ h,
                   const int* __restrict__ indptr, const int* __restrict__ eids,
                   float* __restrict__ a) {
  __shared__ float part[6][PH];
  const int v = blockIdx.x;
  const int t = threadIdx.x;
  const int beg = indptr[v], end = indptr[v + 1];
  if (t < 228) {
    const int g = t % 38;          // 16B granule (8 cols)
    const int s = t / 38;          // row slot 0..5
    const int c8 = g << 3;
    float A[8], B[8];
    #pragma unroll
    for (int q = 0; q < 8; ++q) { A[q] = 0.f; B[q] = 0.f; }
    int p = beg + s;
    for (; p + 12 <= end; p += 12) {
      const int e0 = eids[p], e1 = eids[p + 6];
      GR h0v, h1v;
      h0v.u = *(const uint4*)(h + (size_t)e0 * PH + c8);
      h1v.u = *(const uint4*)(h + (size_t)e1 * PH + c8);
      #pragma unroll
      for (int q = 0; q < 8; ++q) { A[q] += bf2f(h0v.s[q]); B[q] += bf2f(h1v.s[q]); }
    }
    if (p < end) {                 // tail step 1
      GR h0v; h0v.u = *(const uint4*)(h + (size_t)eids[p] * PH + c8);
      #pragma unroll
      for (int q = 0; q < 8; ++q) A[q] += bf2f(h0v.s[q]);
      p += 6;
    }
    if (p < end) {                 // tail step 2
      GR h1v; h1v.u = *(const uint4*)(h + (size_t)eids[p] * PH + c8);
      #pragma unroll
      for (int q = 0; q < 8; ++q) B[q] += bf2f(h1v.s[q]);
    }
    #pragma unroll
    for (int q = 0; q < 8; ++q) part[s][c8 + q] = A[q] + B[q];
  }
  __syncthreads();
  if (t < 76) {
    float4 r = make_float4(0.f, 0.f, 0.f, 0.f);
    #pragma unroll
    for (int s = 0; s < 6; ++s) {
      const float4 pv = *(const float4*)(&part[s][t << 2]);
      r.x += pv.x; r.y += pv.y; r.z += pv.z; r.w += pv.w;
    }
    *(float4*)(a + (size_t)v * PH + (t << 2)) = r;
  }
}

// ---------------- weight pre-transpose into MFMA fragment order -------------
// dst granule (kt,nt,lane l) holds W[kt*32 + (l>>4)*8 + i][nt*16 + (l&15)], i=0..7
__global__ void wtrans_kernel(const float* __restrict__ W, int K,
                              unsigned short* __restrict__ dst) {
  const int b = blockIdx.x;          // kt*NT + nt
  const int l = threadIdx.x;         // 0..63
  const int kt = b / NT, nt = b - kt * NT;
  const int k0 = kt * 32 + ((l >> 4) << 3);
  const int n  = (nt << 4) + (l & 15);
  GR g;
  #pragma unroll
  for (int i = 0; i < 8; ++i) {
    const int k = k0 + i;
    float f = (k < K && n < HID) ? W[(size_t)k * HID + n] : 0.f;
    g.s[i] = f2bf(f);
  }
  *(uint4*)(dst + ((size_t)(b * 64 + l) << 3)) = g.u;
}

// ---------------- MFMA GEMM: 32-row blocks, 16B/lane streams ----------------
// R12 structure (4 waves, acc[5][2], 5 blocks/CU) + G13: all h/h0/a streams
// are 16B/lane on PH=304 padded rows. Pad cols are identically zero.
// MODE 0: edge_init  h0 = relu([x[row]|ea] @ W + b)
// MODE 1: conv       out[e] = relu((a[row[e]] - bf(hcur[e^1])) @ W + b + bf(h0[e]))
// MODE 2: node MLP   hn = relu([x|s] @ W + b)  (f32 out, stride 300)
template<int MODE, int KTILES>
__global__ __launch_bounds__(256, 5)
void gemm_kernel(const float* __restrict__ xin,
                 const int* __restrict__ rowidx,
                 const float* __restrict__ aux,        // MODE0: edge_attr ; MODE2: s[PH]
                 const float* __restrict__ agg,        // MODE1: a[PH] (f32, L3-hot)
                 const unsigned short* hcur,           // MODE1 in (may alias outA)
                 const unsigned short* __restrict__ h0,
                 const unsigned short* __restrict__ wbt,  // fragment-ordered bf16 W^T
                 const float* __restrict__ bias,
                 unsigned short* outA,
                 float* __restrict__ outF)
{
  constexpr int KEFF = (MODE == 0) ? (NF + EF) : ((MODE == 1) ? HID : (NF + HID));
  constexpr int NKG_A = (KEFF + 7) / 8;           // staged 16B k-granules per row
  constexpr int STAGE_USH = NKG_A * BR * 8;
  constexpr int LDS_USH = (MODE == 2) ? STAGE_USH
                        : ((STAGE_USH > BR * CSTRIDE) ? STAGE_USH : BR * CSTRIDE);
  __shared__ unsigned short S_lds[LDS_USH];       // A-stage, then C-tile
  __shared__ int rowv[BR];

  const int t = threadIdx.x;
  const int l = t & 63;
  const int wave = t >> 6;           // 0..3 -> n-tile group
  const int lr = l & 15;             // row within 16-tile
  const int lg = l >> 4;             // k-granule slot / output col-group
  const int r0 = blockIdx.x * BR;
  const int nt0 = wave * 5;
  const int ntc = (wave == 3) ? 4 : 5;

  if (MODE != 2 && t < BR) rowv[t] = rowidx[r0 + t];
  __syncthreads();

  // ---- stage A once into [kg][row]x16B fragment order ----
  if (MODE == 1) {
    // 16B granules: piece P = t + 256*it -> row = t&31 (fixed), kg = (t>>5)+8*it
    const int a_row = t & 31;
    const int kg0   = t >> 5;        // 0..7
    const int rv    = rowv[a_row];
    const float* agp = agg + (size_t)rv * PH;
    const unsigned short* hp = hcur + (size_t)((r0 + a_row) ^ 1) * PH;
    #pragma unroll
    for (int b0 = 0; b0 < 5; b0 += 3) {
      float4 av0[3], av1[3]; GR hv[3];
      #pragma unroll
      for (int j = 0; j < 3; ++j) {
        const int it = b0 + j;
        if (it >= 5) continue;
        const int kg = kg0 + (it << 3);
        if (kg < 38) {
          const int k = kg << 3;
          av0[j] = *(const float4*)(agp + k);
          av1[j] = *(const float4*)(agp + k + 4);
          hv[j].u = *(const uint4*)(hp + k);
        }
      }
      #pragma unroll
      for (int j = 0; j < 3; ++j) {
        const int it = b0 + j;
        if (it >= 5) continue;
        const int kg = kg0 + (it << 3);
        if (kg >= 38) continue;
        GR o;
        const float* a0 = (const float*)&av0[j];
        const float* a1 = (const float*)&av1[j];
        #pragma unroll
        for (int q = 0; q < 4; ++q) o.s[q] = f2bf(a0[q] - bf2f(hv[j].s[q]));
        #pragma unroll
        for (int q = 0; q < 4; ++q) o.s[4 + q] = f2bf(a1[q] - bf2f(hv[j].s[4 + q]));
        *(uint4*)(S_lds + (size_t)((kg << 5) + a_row) * 8) = o.u;
      }
    }
  } else {
    // MODE 0 / 2: f32 feature concat -> bf16, 8B pieces (small contributors)
    constexpr int PIECES = STAGE_USH / 4;
    constexpr int SITER = (PIECES + 255) / 256;
    const int a_row = (t >> 1) & 31;
    const int a_c   = t >> 6;        // 0..3
    const int a_h4  = (t & 1) << 2;
    const int rv    = (MODE == 2) ? (r0 + a_row) : rowv[a_row];
    const float* xp = xin + (size_t)rv * NF;
    const float* ap = (MODE == 0) ? aux + (size_t)(r0 + a_row) * EF - NF
                                  : aux + (size_t)rv * PH - NF;
    const bool node_ok = (MODE != 2) || (rv < NN);
    #pragma unroll
    for (int b0 = 0; b0 < SITER; b0 += 4) {
      float fv[4][4];
      #pragma unroll
      for (int j = 0; j < 4; ++j) {
        const int it = b0 + j;
        if (it >= SITER) continue;
        const bool ok = (t + (it << 8)) < PIECES;
        const int k = ((a_c + 4 * it) << 3) + a_h4;
        #pragma unroll
        for (int q = 0; q < 4; ++q) {
          const int kk = k + q;
          float f = 0.f;
          if (ok && node_ok) {
            if (kk < NF) f = xp[kk];
            else if (kk < KEFF) f = ap[kk];
          }
          fv[j][q] = f;
        }
      }
      #pragma unroll
      for (int j = 0; j < 4; ++j) {
        const int it = b0 + j;
        if (it >= SITER) continue;
        if ((t + (it << 8)) >= PIECES) continue;
        ushort4 o;
        o.x = f2bf(fv[j][0]); o.y = f2bf(fv[j][1]);
        o.z = f2bf(fv[j][2]); o.w = f2bf(fv[j][3]);
        *(ushort4*)(S_lds + (size_t)(t + (it << 8)) * 4) = o;
      }
    }
  }
  __syncthreads();

  f32x4 acc[5][2];
  #pragma unroll
  for (int ni = 0; ni < 5; ++ni)
    #pragma unroll
    for (int i = 0; i < 2; ++i) acc[ni][i] = (f32x4)0.f;

  // ---- barrier-free k-loop (ntc-guarded; compiler-scheduled) ----
  #pragma unroll
  for (int kt = 0; kt < KTILES; ++kt) {
    int kg = kt * 4 + lg;
    if (kt * 4 + 3 >= NKG_A) kg = (kg < NKG_A) ? kg : 0;   // compile-time guard on kt
    bf16x8 ef[2];
    #pragma unroll
    for (int i = 0; i < 2; ++i)
      ef[i] = *(const bf16x8*)(S_lds + (size_t)((kg * BR + i * 16 + lr)) * 8);
    const unsigned short* wk = wbt + (((size_t)kt * WGRAN + nt0 * 64 + l) << 3);
    #pragma unroll
    for (int ni = 0; ni < 5; ++ni) {
      if (ni < ntc) {
        const bf16x8 wf = *(const bf16x8*)(wk + ((size_t)ni << 9));
        #pragma unroll
        for (int i = 0; i < 2; ++i)
          acc[ni][i] = __builtin_amdgcn_mfma_f32_16x16x32_bf16(wf, ef[i], acc[ni][i], 0, 0, 0);
      }
    }
  }

  if (MODE == 2) {
    // direct scattered epilogue (313 blocks, 12 MB out, stride 300)
    #pragma unroll
    for (int ni = 0; ni < 5; ++ni) {
      if (ni >= ntc) continue;
      const int n = ((nt0 + ni) << 4) + (lg << 2);
      if (n >= HID) continue;
      const float4 bv = *(const float4*)(bias + n);
      #pragma unroll
      for (int i = 0; i < 2; ++i) {
        const int node = r0 + (i << 4) + lr;
        if (node >= NN) continue;
        float v0 = fmaxf(acc[ni][i][0] + bv.x, 0.f);
        float v1 = fmaxf(acc[ni][i][1] + bv.y, 0.f);
        float v2 = fmaxf(acc[ni][i][2] + bv.z, 0.f);
        float v3 = fmaxf(acc[ni][i][3] + bv.w, 0.f);
        *(float4*)(outF + (size_t)node * HID + n) = make_float4(v0, v1, v2, v3);
      }
    }
    return;
  }

  // ---- stage C tile (acc + bias, pre-relu) into LDS (reuses S_lds) ----
  __syncthreads();   // all fragment reads done before overwrite
  #pragma unroll
  for (int ni = 0; ni < 5; ++ni) {
    if (ni >= ntc) continue;
    const int n = ((nt0 + ni) << 4) + (lg << 2);
    float4 bv = make_float4(0.f, 0.f, 0.f, 0.f);
    if (n < HID) bv = *(const float4*)(bias + n);   // pad cols get 0 bias
    #pragma unroll
    for (int i = 0; i < 2; ++i) {
      const int row = (i << 4) + lr;
      ushort4 o;
      o.x = f2bf(acc[ni][i][0] + bv.x);
      o.y = f2bf(acc[ni][i][1] + bv.y);
      o.z = f2bf(acc[ni][i][2] + bv.z);
      o.w = f2bf(acc[ni][i][3] + bv.w);
      *(ushort4*)(S_lds + row * CSTRIDE + n) = o;   // n <= 300, fits 304
    }
  }
  __syncthreads();

  // ---- linear write-out, 16B/lane: 32 rows x 38 uint4 granules ----
  {
    const size_t base = (size_t)r0 * PH;
    constexpr int WPIECE = BR * 38;               // 1216
    GR hz[5];
    int srow[5], sidx[5]; bool ok[5];
    #pragma unroll
    for (int j = 0; j < 5; ++j) {
      const int s = t + (j << 8);
      ok[j] = (s < WPIECE);
      if (ok[j]) {
        srow[j] = s / 38; sidx[j] = s - srow[j] * 38;
        if (MODE == 1)
          hz[j].u = *(const uint4*)(h0 + base + (size_t)srow[j] * PH + (sidx[j] << 3));
      }
    }
    #pragma unroll
    for (int j = 0; j < 5; ++j) {
      if (!ok[j]) continue;
      GR c; c.u = *(const uint4*)(S_lds + srow[j] * CSTRIDE + (sidx[j] << 3));
      GR o;
      #pragma unroll
      for (int q = 0; q < 8; ++q) {
        float v = bf2f(c.s[q]);
        if (MODE == 1) v += bf2f(hz[j].s[q]);
        o.s[q] = f2bf(fmaxf(v, 0.f));
      }
      *(uint4*)(outA + base + (size_t)srow[j] * PH + (sidx[j] << 3)) = o.u;
    }
  }
}

// ---------------- output init + fused dot/pool ----------------
__global__ void init_out_kernel(float* __restrict__ out, const float* __restrict__ b_ffn) {
  int t = threadIdx.x;
  if (t < NG) out[t] = b_ffn[0];
}

__global__ void dotpool_kernel(const float* __restrict__ hn, const float* __restrict__ wffn,
                               const int* __restrict__ batch, float* __restrict__ out) {
  const int wave = threadIdx.x >> 6, lane = threadIdx.x & 63;
  const int v = blockIdx.x * 4 + wave;
  if (v >= NN) return;
  float s = 0.f;
  for (int j = lane; j < HID; j += 64) s += hn[(size_t)v * HID + j] * wffn[j];
  #pragma unroll
  for (int off = 32; off > 0; off >>= 1) s += __shfl_down(s, off, 64);
  if (lane == 0) atomicAdd(&out[batch[v]], s);
}

// ---------------- launch ----------------
extern "C" void kernel_launch(void* const* d_in, const int* in_sizes, int n_in,
                              void* d_out, int out_size, void* d_ws, size_t ws_size,
                              hipStream_t stream) {
  const float* x     = (const float*)d_in[0];
  const int*   eidx  = (const int*)d_in[1];
  const float* eattr = (const float*)d_in[2];
  const int*   batch = (const int*)d_in[3];
  const float* W_ei  = (const float*)d_in[4];
  const float* b_ei  = (const float*)d_in[5];
  const float* Ws    = (const float*)d_in[6];
  const float* bs    = (const float*)d_in[7];
  const float* W_en  = (const float*)d_in[8];
  const float* b_en  = (const float*)d_in[9];
  const float* W_ffn = (const float*)d_in[10];
  const float* b_ffn = (const float*)d_in[11];
  float* out = (float*)d_out;

  const int* row  = eidx;
  const int* colv = eidx + NE;

  // workspace layout (~220 MB), all PH=304-stride rows 16B-aligned
  char* ws = (char*)d_ws;
  unsigned short* h0 = (unsigned short*)(ws + 0);              //  97,280,000 B
  unsigned short* h  = (unsigned short*)(ws + 97280000ull);    //  97,280,000 B
  float* abuf        = (float*)(ws + 194560000ull);            //  12,160,000 B
  float* hn          = (float*)(ws + 206720000ull);            //  12,000,000 B (stride 300)
  int* indptr        = (int*)(ws + 218720000ull);              //      40,004 B
  int* cnt           = (int*)(ws + 218760192ull);              //      40,000 B
  int* eids          = (int*)(ws + 218800384ull);              //     640,000 B
  unsigned short* wbt0 = (unsigned short*)(ws + 219440384ull); //      97,280 B (5 kt)
  unsigned short* wbtC = (unsigned short*)(ws + 219537664ull); //  3x 194,560 B (10 kt)
  unsigned short* wbtN = (unsigned short*)(ws + 220121344ull); //     272,384 B (14 kt)

  // CSR over col (scatter restores cnt to 0)
  zero_kernel<<<(NN + 255) / 256, 256, 0, stream>>>(cnt, NN);
  hist_kernel<<<NE / 256, 256, 0, stream>>>(colv, cnt);
  scan_kernel<<<1, 1024, 0, stream>>>(cnt, indptr);
  scatter_kernel<<<NE / 256, 256, 0, stream>>>(colv, indptr, cnt, eids);

  // weight pre-transposes (bf16, MFMA fragment order, zero-padded tails)
  wtrans_kernel<<<5 * NT, 64, 0, stream>>>(W_ei, NF + EF, wbt0);
  for (int lyr = 0; lyr < 3; ++lyr)
    wtrans_kernel<<<10 * NT, 64, 0, stream>>>(Ws + (size_t)lyr * HID * HID, HID,
                                              wbtC + (size_t)lyr * 10 * WGRAN * 8);
  wtrans_kernel<<<14 * NT, 64, 0, stream>>>(W_en, NF + HID, wbtN);

  // h0 = relu([x[row]|ea] @ W_ei + b_ei)  (pad cols 300-303 written as 0)
  gemm_kernel<0, 5><<<NE / BR, 256, 0, stream>>>(
      x, row, eattr, nullptr, nullptr, nullptr, wbt0, b_ei, h0, nullptr);

  // layer 0: a = segsum(h0); h = relu((a[row]-h0[e^1])@W0 + b0 + h0)
  segsum_kernel<<<NN, 256, 0, stream>>>(h0, indptr, eids, abuf);
  gemm_kernel<1, 10><<<NE / BR, 256, 0, stream>>>(
      nullptr, row, nullptr, abuf, h0, h0, wbtC, bs, h, nullptr);

  // layers 1,2: in-place on h
  for (int lyr = 1; lyr < 3; ++lyr) {
    segsum_kernel<<<NN, 256, 0, stream>>>(h, indptr, eids, abuf);
    gemm_kernel<1, 10><<<NE / BR, 256, 0, stream>>>(
        nullptr, row, nullptr, abuf, h, h0,
        wbtC + (size_t)lyr * 10 * WGRAN * 8, bs + (size_t)lyr * HID,
        h, nullptr);
  }

  // s = segsum(h, col); hn = relu([x|s] @ W_en + b_en)
  segsum_kernel<<<NN, 256, 0, stream>>>(h, indptr, eids, abuf);
  gemm_kernel<2, 14><<<(NN + BR - 1) / BR, 256, 0, stream>>>(
      x, nullptr, abuf, nullptr, nullptr, nullptr, wbtN, b_en,
      nullptr, hn);

  // out[g] = b_ffn + sum_{batch[v]=g} hn[v] . W_ffn
  init_out_kernel<<<1, 64, 0, stream>>>(out, b_ffn);
  dotpool_kernel<<<NN / 4, 256, 0, stream>>>(hn, W_ffn, batch, out);
}